// Round 5
// baseline (206.406 us; speedup 1.0000x reference)
//
#include <hip/hip_runtime.h>

typedef __attribute__((ext_vector_type(8))) short short8v;
typedef __attribute__((ext_vector_type(4))) float f32x4;

#define BATCH 128
#define CIN 8
#define HW 128
#define COUT 64
#define OHW 126
#define PH 31
#define GN_EPS 1e-5f

#define ROWS_A 8
#define STRIPS_A 16
#define INROWS_A 11   // 10 real (clipped) + 1 zero row
#define INROWS_B 7    // 6 real + 1 zero row
#define ACOLS 132

static __device__ __forceinline__ unsigned short f2bf(float f) {
    unsigned u = __float_as_uint(f);
    return (unsigned short)((u + 0x7fffu + ((u >> 16) & 1u)) >> 16);
}
static __device__ __forceinline__ unsigned pk2(float a, float b) {
    return (unsigned)f2bf(a) | ((unsigned)f2bf(b) << 16);
}

// ---- prep: pack weights into MFMA B-fragment order, bf16 ----
__global__ __launch_bounds__(256) void prep_weights(const float* __restrict__ w,
                                                    short* __restrict__ Bpack)
{
    for (int e = threadIdx.x; e < 3 * 4 * 64; e += 256) {
        int dx = e >> 8;
        int nt = (e >> 6) & 3;
        int l  = e & 63;
        int i = l & 15, g = l >> 4;
        int n = nt * 16 + i;
        #pragma unroll
        for (int j = 0; j < 8; ++j) {
            float v = (g < 3) ? w[((n * CIN + j) * 3 + g) * 3 + dx] : 0.f;
            Bpack[e * 8 + j] = (short)f2bf(v);
        }
    }
}

// ---- pass A: bf16-MFMA conv (no bias) + per-(b,channel) partial stats ----
// Staging: ONE column-entry per loop iteration, 8 scalar loads (round-2-proven:
// coalesced across lanes, no wide-vector register pressure, no scratch).
__global__ __launch_bounds__(256, 4) void conv_stats(
    const float* __restrict__ x, const short* __restrict__ Bpack,
    float* __restrict__ part)
{
    __shared__ __align__(16) short Abuf[INROWS_A][ACOLS][8];
    __shared__ float red[4][COUT][2];
    const int strip = blockIdx.x, b = blockIdx.y;
    const int tid = threadIdx.x, wave = tid >> 6, lane = tid & 63;
    const int i = lane & 15, g = lane >> 4;
    const int r0 = strip * ROWS_A;

    {
        const float* xb = x + (size_t)b * CIN * HW * HW;
        for (int e = tid; e < INROWS_A * ACOLS; e += 256) {
            int row = e / ACOLS, col = e % ACOLS;
            int ri = r0 + row;
            bool ok = (row < 10) && (ri < HW) && (col < HW);
            const float* base = &xb[(size_t)ri * HW + col];
            float v0 = ok ? base[0 * HW * HW] : 0.f;
            float v1 = ok ? base[1 * HW * HW] : 0.f;
            float v2 = ok ? base[2 * HW * HW] : 0.f;
            float v3 = ok ? base[3 * HW * HW] : 0.f;
            float v4 = ok ? base[4 * HW * HW] : 0.f;
            float v5 = ok ? base[5 * HW * HW] : 0.f;
            float v6 = ok ? base[6 * HW * HW] : 0.f;
            float v7 = ok ? base[7 * HW * HW] : 0.f;
            uint4 u;
            u.x = pk2(v0, v1); u.y = pk2(v2, v3);
            u.z = pk2(v4, v5); u.w = pk2(v6, v7);
            *(uint4*)&Abuf[row][col][0] = u;
        }
    }

    // B fragments (12 x 16B)
    short8v bq[3][4];
    {
        const uint4* bp = (const uint4*)Bpack;
        #pragma unroll
        for (int dx = 0; dx < 3; ++dx)
            #pragma unroll
            for (int nt = 0; nt < 4; ++nt) {
                uint4 t4 = bp[(dx * 4 + nt) * 64 + lane];
                bq[dx][nt] = *(short8v*)&t4;
            }
    }
    __syncthreads();

    float s1[4] = {0.f, 0.f, 0.f, 0.f}, s2[4] = {0.f, 0.f, 0.f, 0.f};
    const short* zp = &Abuf[INROWS_A - 1][0][0];
    #pragma unroll
    for (int rr = 0; rr < 2; ++rr) {
        const int rloc = wave + rr * 4;
        if (r0 + rloc < OHW) {
            for (int t = 0; t < 8; ++t) {
                f32x4 acc[4];
                #pragma unroll
                for (int nt = 0; nt < 4; ++nt) acc[nt] = (f32x4){0.f, 0.f, 0.f, 0.f};
                #pragma unroll
                for (int dx = 0; dx < 3; ++dx) {
                    const short* ap = &Abuf[rloc + g][16 * t + i + dx][0];
                    if (t == 7 && i >= 14) ap = zp;  // cols 126,127 -> zero A rows
                    short8v a = *(const short8v*)ap;
                    #pragma unroll
                    for (int nt = 0; nt < 4; ++nt)
                        acc[nt] = __builtin_amdgcn_mfma_f32_16x16x32_bf16(a, bq[dx][nt], acc[nt], 0, 0, 0);
                }
                #pragma unroll
                for (int nt = 0; nt < 4; ++nt)
                    #pragma unroll
                    for (int r = 0; r < 4; ++r) {
                        float vv = acc[nt][r];
                        s1[nt] += vv;
                        s2[nt] = fmaf(vv, vv, s2[nt]);
                    }
            }
        }
    }

    // sum over m-rows (g) only; keep per-channel
    #pragma unroll
    for (int nt = 0; nt < 4; ++nt) {
        s1[nt] += __shfl_xor(s1[nt], 16); s1[nt] += __shfl_xor(s1[nt], 32);
        s2[nt] += __shfl_xor(s2[nt], 16); s2[nt] += __shfl_xor(s2[nt], 32);
    }
    if (g == 0) {
        #pragma unroll
        for (int nt = 0; nt < 4; ++nt) {
            red[wave][nt * 16 + i][0] = s1[nt];
            red[wave][nt * 16 + i][1] = s2[nt];
        }
    }
    __syncthreads();
    if (tid < 128) {
        int c = tid >> 1, w = tid & 1;
        float v = red[0][c][w] + red[1][c][w] + red[2][c][w] + red[3][c][w];
        part[(((size_t)b * STRIPS_A + strip) * COUT + c) * 2 + w] = v;
    }
}

// ---- fold stats + bias into per-(b,c) affine A, B2 ----
__global__ __launch_bounds__(256) void finalize_stats(
    const float* __restrict__ part, const float* __restrict__ gnw,
    const float* __restrict__ gnb, const float* __restrict__ scale,
    const float* __restrict__ bias, float* __restrict__ Aarr, float* __restrict__ B2arr)
{
    int t = blockIdx.x * 256 + threadIdx.x;  // 8192 = 128 b * 64 c
    int b = t >> 6, c = t & 63;
    float s1 = 0.f, s2 = 0.f;
    for (int s = 0; s < STRIPS_A; ++s) {
        const float* p = &part[(((size_t)b * STRIPS_A + s) * COUT + c) * 2];
        s1 += p[0]; s2 += p[1];
    }
    const float Nf = (float)(OHW * OHW);
    float bc = bias[c];
    float S2 = s2 + 2.f * bc * s1 + Nf * bc * bc;
    float S1 = s1 + Nf * bc;
    float G1 = S1 + __shfl_xor(S1, 1); G1 += __shfl_xor(G1, 2);
    float G2 = S2 + __shfl_xor(S2, 1); G2 += __shfl_xor(G2, 2);
    float invN = 1.f / (4.f * Nf);
    float mean = G1 * invN;
    float var = G2 * invN - mean * mean;
    float rstd = rsqrtf(var + GN_EPS);
    float A = rstd * gnw[c] * scale[c];
    float B2 = (gnb[c] - mean * rstd * gnw[c]) * scale[c] + bc * A;
    Aarr[t] = A;
    B2arr[t] = B2;
}

// Stage one (row, col0..col0+3) entry: 8 named float4 loads -> 4 uint4 LDS stores.
// Used ONLY in conv_pool where each thread stages at most one entry (no loop,
// no software-pipelining pressure) — proven fast in round 3/4.
#define STAGE_ENTRY(Abuf, xb, row, col0, okexpr)                               \
    {                                                                          \
        float4 v0, v1, v2, v3, v4, v5, v6, v7;                                 \
        if (okexpr) {                                                          \
            const float* bsp = &(xb)[(size_t)(ri) * HW + (col0)];              \
            v0 = *(const float4*)&bsp[0 * HW * HW];                            \
            v1 = *(const float4*)&bsp[1 * HW * HW];                            \
            v2 = *(const float4*)&bsp[2 * HW * HW];                            \
            v3 = *(const float4*)&bsp[3 * HW * HW];                            \
            v4 = *(const float4*)&bsp[4 * HW * HW];                            \
            v5 = *(const float4*)&bsp[5 * HW * HW];                            \
            v6 = *(const float4*)&bsp[6 * HW * HW];                            \
            v7 = *(const float4*)&bsp[7 * HW * HW];                            \
        } else {                                                               \
            v0 = v1 = v2 = v3 = v4 = v5 = v6 = v7 = make_float4(0.f,0.f,0.f,0.f); \
        }                                                                      \
        uint4 u;                                                               \
        u.x = pk2(v0.x, v1.x); u.y = pk2(v2.x, v3.x);                          \
        u.z = pk2(v4.x, v5.x); u.w = pk2(v6.x, v7.x);                          \
        *(uint4*)&Abuf[row][(col0) + 0][0] = u;                                \
        u.x = pk2(v0.y, v1.y); u.y = pk2(v2.y, v3.y);                          \
        u.z = pk2(v4.y, v5.y); u.w = pk2(v6.y, v7.y);                          \
        *(uint4*)&Abuf[row][(col0) + 1][0] = u;                                \
        u.x = pk2(v0.z, v1.z); u.y = pk2(v2.z, v3.z);                          \
        u.z = pk2(v4.z, v5.z); u.w = pk2(v6.z, v7.z);                          \
        *(uint4*)&Abuf[row][(col0) + 2][0] = u;                                \
        u.x = pk2(v0.w, v1.w); u.y = pk2(v2.w, v3.w);                          \
        u.z = pk2(v4.w, v5.w); u.w = pk2(v6.w, v7.w);                          \
        *(uint4*)&Abuf[row][(col0) + 3][0] = u;                                \
    }

// ---- pass B: bf16-MFMA conv + affine + in-register maxpool + clamp ----
__global__ __launch_bounds__(256, 4) void conv_pool(
    const float* __restrict__ x, const short* __restrict__ Bpack,
    const float* __restrict__ Aarr, const float* __restrict__ B2arr,
    float* __restrict__ out)
{
    __shared__ __align__(16) short Abuf[INROWS_B][ACOLS][8];
    const int prow = blockIdx.x, b = blockIdx.y;
    const int tid = threadIdx.x, wave = tid >> 6, lane = tid & 63;
    const int i = lane & 15, g = lane >> 4;
    const int r0 = prow * 4;

    {
        const float* xb = x + (size_t)b * CIN * HW * HW;
        if (tid < INROWS_B * 33) {
            int row = tid / 33, cg = tid % 33;
            int col0 = cg << 2;
            int ri = r0 + row;
            STAGE_ENTRY(Abuf, xb, row, col0, (row < 6 && cg < 32));
        }
    }

    short8v bq[3][4];
    {
        const uint4* bp = (const uint4*)Bpack;
        #pragma unroll
        for (int dx = 0; dx < 3; ++dx)
            #pragma unroll
            for (int nt = 0; nt < 4; ++nt) {
                uint4 t4 = bp[(dx * 4 + nt) * 64 + lane];
                bq[dx][nt] = *(short8v*)&t4;
            }
    }
    float Ac[4], Bc[4];
    #pragma unroll
    for (int nt = 0; nt < 4; ++nt) {
        Ac[nt] = Aarr[b * COUT + nt * 16 + i];
        Bc[nt] = B2arr[b * COUT + nt * 16 + i];
    }
    __syncthreads();

    for (int tp = 0; tp < 2; ++tp) {
        const int tg = 2 * wave + tp;           // col tile 16*tg
        f32x4 pm[4];
        #pragma unroll
        for (int nt = 0; nt < 4; ++nt) pm[nt] = (f32x4){-1e30f, -1e30f, -1e30f, -1e30f};

        #pragma unroll
        for (int p = 0; p < 2; ++p) {           // conv-row pairs {0,1},{2,3}
            f32x4 acc[2][4];
            #pragma unroll
            for (int rr = 0; rr < 2; ++rr)
                #pragma unroll
                for (int nt = 0; nt < 4; ++nt) acc[rr][nt] = (f32x4){0.f, 0.f, 0.f, 0.f};
            #pragma unroll
            for (int rr = 0; rr < 2; ++rr) {
                const int r = 2 * p + rr;
                #pragma unroll
                for (int dx = 0; dx < 3; ++dx) {
                    short8v a = *(const short8v*)&Abuf[r + g][16 * tg + i + dx][0];
                    #pragma unroll
                    for (int nt = 0; nt < 4; ++nt)
                        acc[rr][nt] = __builtin_amdgcn_mfma_f32_16x16x32_bf16(a, bq[dx][nt], acc[rr][nt], 0, 0, 0);
                }
            }
            #pragma unroll
            for (int nt = 0; nt < 4; ++nt)
                #pragma unroll
                for (int k = 0; k < 4; ++k) {
                    float e0 = fmaf(acc[0][nt][k], Ac[nt], Bc[nt]);
                    float e1 = fmaf(acc[1][nt][k], Ac[nt], Bc[nt]);
                    pm[nt][k] = fmaxf(pm[nt][k], fmaxf(e0, e1));
                }
        }
        const int pc = 4 * tg + g;
        if (pc < PH) {
            #pragma unroll
            for (int nt = 0; nt < 4; ++nt) {
                float m = fmaxf(fmaxf(pm[nt][0], pm[nt][1]), fmaxf(pm[nt][2], pm[nt][3]));
                m = fminf(fmaxf(m, 0.f), 1.f);
                out[((size_t)(b * COUT + nt * 16 + i) * PH + prow) * PH + pc] = m;
            }
        }
    }
}

extern "C" void kernel_launch(void* const* d_in, const int* in_sizes, int n_in,
                              void* d_out, int out_size, void* d_ws, size_t ws_size,
                              hipStream_t stream)
{
    const float* x   = (const float*)d_in[0];
    const float* w   = (const float*)d_in[1];
    const float* cbv = (const float*)d_in[2];
    const float* gnw = (const float*)d_in[3];
    const float* gnb = (const float*)d_in[4];
    const float* sc  = (const float*)d_in[5];
    float* out = (float*)d_out;

    float* part  = (float*)d_ws;                                  // 128*16*64*2 f32
    float* Aarr  = part + (size_t)BATCH * STRIPS_A * COUT * 2;
    float* B2arr = Aarr + BATCH * COUT;
    short* Bpack = (short*)(B2arr + BATCH * COUT);

    prep_weights<<<dim3(1), 256, 0, stream>>>(w, Bpack);
    conv_stats<<<dim3(STRIPS_A, BATCH), 256, 0, stream>>>(x, Bpack, part);
    finalize_stats<<<dim3(32), 256, 0, stream>>>(part, gnw, gnb, sc, cbv, Aarr, B2arr);
    conv_pool<<<dim3(PH, BATCH), 256, 0, stream>>>(x, Bpack, Aarr, B2arr, out);
}

// Round 6
// 84.902 us; speedup vs baseline: 2.4311x; 2.4311x over previous
//
#include <hip/hip_runtime.h>

typedef __attribute__((ext_vector_type(8))) short short8v;
typedef __attribute__((ext_vector_type(4))) float f32x4;
typedef __attribute__((ext_vector_type(4))) int i32x4;

#define BATCH 128
#define CIN 8
#define HW 128
#define COUT 64
#define OHW 126
#define NG 16
#define PH 31
#define GN_EPS 1e-5f

#define ROWS_A 8
#define STRIPS_A 16
#define INROWS_A 11   // 10 real + 1 zero pad (for g=3 reads)
#define INROWS_B 7    // 6 real + 1 zero pad
#define ACOLS 132

static __device__ __forceinline__ unsigned short f2bf(float f) {
    unsigned u = __float_as_uint(f);
    return (unsigned short)((u + 0x7fffu + ((u >> 16) & 1u)) >> 16);
}
static __device__ __forceinline__ unsigned pk2(float a, float b) {
    return (unsigned)f2bf(a) | ((unsigned)f2bf(b) << 16);
}

// ---- prep: pack weights into MFMA B-fragment order, bf16 ----
__global__ __launch_bounds__(256) void prep_weights(const float* __restrict__ w,
                                                    short* __restrict__ Bpack)
{
    for (int e = threadIdx.x; e < 3 * 4 * 64; e += 256) {
        int dx = e >> 8;
        int nt = (e >> 6) & 3;
        int l  = e & 63;
        int i = l & 15, g = l >> 4;
        int n = nt * 16 + i;
        #pragma unroll
        for (int j = 0; j < 8; ++j) {
            float v = (g < 3) ? w[((n * CIN + j) * 3 + g) * 3 + dx] : 0.f;
            Bpack[e * 8 + j] = (short)f2bf(v);
        }
    }
}

// ---- pass A (round-2 proven verbatim): bf16-MFMA conv + per-(b,group) partial stats ----
__global__ __launch_bounds__(256, 4) void conv_stats(
    const float* __restrict__ x, const short* __restrict__ Bpack,
    const float* __restrict__ bias, float* __restrict__ part)
{
    __shared__ __align__(16) short Abuf[INROWS_A][ACOLS][8];
    __shared__ float red[4][NG][2];
    const int strip = blockIdx.x, b = blockIdx.y;
    const int tid = threadIdx.x, wave = tid >> 6, lane = tid & 63;
    const int i = lane & 15, g = lane >> 4;
    const int r0 = strip * ROWS_A;

    // B fragments into registers (12 x 16B)
    short8v bq[3][4];
    {
        const i32x4* bp = (const i32x4*)Bpack;
        #pragma unroll
        for (int dx = 0; dx < 3; ++dx)
            #pragma unroll
            for (int nt = 0; nt < 4; ++nt) {
                i32x4 v = bp[(dx * 4 + nt) * 64 + lane];
                bq[dx][nt] = *(short8v*)&v;
            }
    }
    float bs[4];
    #pragma unroll
    for (int nt = 0; nt < 4; ++nt) bs[nt] = bias[nt * 16 + i];

    // build Abuf[row][col][cin] (bf16), zero-padded
    {
        const float* xb = x + (size_t)b * CIN * HW * HW;
        for (int e = tid; e < INROWS_A * ACOLS; e += 256) {
            int row = e / ACOLS, col = e % ACOLS;
            int ri = r0 + row;
            bool ok = (row < 10) && (ri < HW) && (col < HW);
            unsigned pk0, pk1, pk2_, pk3;
            {
                const float* base = &xb[(size_t)ri * HW + col];
                float v0 = ok ? base[0 * HW * HW] : 0.f;
                float v1 = ok ? base[1 * HW * HW] : 0.f;
                float v2 = ok ? base[2 * HW * HW] : 0.f;
                float v3 = ok ? base[3 * HW * HW] : 0.f;
                float v4 = ok ? base[4 * HW * HW] : 0.f;
                float v5 = ok ? base[5 * HW * HW] : 0.f;
                float v6 = ok ? base[6 * HW * HW] : 0.f;
                float v7 = ok ? base[7 * HW * HW] : 0.f;
                pk0  = pk2(v0, v1);
                pk1  = pk2(v2, v3);
                pk2_ = pk2(v4, v5);
                pk3  = pk2(v6, v7);
            }
            uint4 w4 = make_uint4(pk0, pk1, pk2_, pk3);
            *(uint4*)&Abuf[row][col][0] = w4;
        }
    }
    __syncthreads();

    float s1[4] = {0.f, 0.f, 0.f, 0.f}, s2[4] = {0.f, 0.f, 0.f, 0.f};
    #pragma unroll
    for (int rr = 0; rr < 2; ++rr) {
        const int rloc = wave + rr * 4;
        const int R = r0 + rloc;
        if (R < OHW) {
            for (int t = 0; t < 8; ++t) {
                f32x4 acc[4];
                #pragma unroll
                for (int nt = 0; nt < 4; ++nt) acc[nt] = (f32x4){0.f, 0.f, 0.f, 0.f};
                #pragma unroll
                for (int dx = 0; dx < 3; ++dx) {
                    short8v a = *(const short8v*)&Abuf[rloc + g][16 * t + i + dx][0];
                    #pragma unroll
                    for (int nt = 0; nt < 4; ++nt)
                        acc[nt] = __builtin_amdgcn_mfma_f32_16x16x32_bf16(a, bq[dx][nt], acc[nt], 0, 0, 0);
                }
                const int nv = (t == 7 && g == 3) ? 2 : 4;  // cols >=126 invalid
                #pragma unroll
                for (int nt = 0; nt < 4; ++nt)
                    #pragma unroll
                    for (int r = 0; r < 4; ++r)
                        if (r < nv) {
                            float v = acc[nt][r] + bs[nt];
                            s1[nt] += v;
                            s2[nt] = fmaf(v, v, s2[nt]);
                        }
            }
        }
    }

    // reduce over m (g: xor 16,32) and over group-quad channels (i&3: xor 1,2)
    #pragma unroll
    for (int nt = 0; nt < 4; ++nt) {
        s1[nt] += __shfl_xor(s1[nt], 1);  s1[nt] += __shfl_xor(s1[nt], 2);
        s1[nt] += __shfl_xor(s1[nt], 16); s1[nt] += __shfl_xor(s1[nt], 32);
        s2[nt] += __shfl_xor(s2[nt], 1);  s2[nt] += __shfl_xor(s2[nt], 2);
        s2[nt] += __shfl_xor(s2[nt], 16); s2[nt] += __shfl_xor(s2[nt], 32);
    }
    if (g == 0 && (i & 3) == 0) {
        #pragma unroll
        for (int nt = 0; nt < 4; ++nt) {
            red[wave][nt * 4 + (i >> 2)][0] = s1[nt];
            red[wave][nt * 4 + (i >> 2)][1] = s2[nt];
        }
    }
    __syncthreads();
    if (tid < 32) {
        int grp = tid >> 1, which = tid & 1;
        float v = red[0][grp][which] + red[1][grp][which] + red[2][grp][which] + red[3][grp][which];
        part[(((size_t)b * STRIPS_A + strip) * NG + grp) * 2 + which] = v;
    }
}

// ---- fold stats into per-(b,c) affine: A, B2 (bias folded in) — round-2 verbatim ----
__global__ __launch_bounds__(256) void finalize_stats(
    const float* __restrict__ part, const float* __restrict__ gnw,
    const float* __restrict__ gnb, const float* __restrict__ scale,
    const float* __restrict__ bias, float* __restrict__ Aarr, float* __restrict__ B2arr)
{
    int t = blockIdx.x * 256 + threadIdx.x;
    if (t >= BATCH * NG) return;
    int b = t >> 4, grp = t & 15;
    float s1 = 0.f, s2 = 0.f;
    for (int s = 0; s < STRIPS_A; ++s) {
        s1 += part[(((size_t)b * STRIPS_A + s) * NG + grp) * 2 + 0];
        s2 += part[(((size_t)b * STRIPS_A + s) * NG + grp) * 2 + 1];
    }
    const float invN = 1.f / (float)(4 * OHW * OHW);
    float mean = s1 * invN;
    float var = s2 * invN - mean * mean;
    float rstd = rsqrtf(var + GN_EPS);
    #pragma unroll
    for (int ci = 0; ci < 4; ++ci) {
        int c = grp * 4 + ci;
        float A = rstd * gnw[c] * scale[c];
        float Bv = (gnb[c] - mean * rstd * gnw[c]) * scale[c];
        Aarr[b * COUT + c] = A;
        B2arr[b * COUT + c] = Bv + bias[c] * A;
    }
}

// Stage one (row, col0..col0+3) entry: 8 named float4 loads -> 4 uint4 LDS stores.
// Used ONLY in conv_pool: each thread stages at most one entry (no loop).
#define STAGE_ENTRY(Abuf, xb, row, col0, okexpr)                               \
    {                                                                          \
        float4 v0, v1, v2, v3, v4, v5, v6, v7;                                 \
        if (okexpr) {                                                          \
            const float* bsp = &(xb)[(size_t)(ri) * HW + (col0)];              \
            v0 = *(const float4*)&bsp[0 * HW * HW];                            \
            v1 = *(const float4*)&bsp[1 * HW * HW];                            \
            v2 = *(const float4*)&bsp[2 * HW * HW];                            \
            v3 = *(const float4*)&bsp[3 * HW * HW];                            \
            v4 = *(const float4*)&bsp[4 * HW * HW];                            \
            v5 = *(const float4*)&bsp[5 * HW * HW];                            \
            v6 = *(const float4*)&bsp[6 * HW * HW];                            \
            v7 = *(const float4*)&bsp[7 * HW * HW];                            \
        } else {                                                               \
            v0 = v1 = v2 = v3 = v4 = v5 = v6 = v7 = make_float4(0.f,0.f,0.f,0.f); \
        }                                                                      \
        uint4 u;                                                               \
        u.x = pk2(v0.x, v1.x); u.y = pk2(v2.x, v3.x);                          \
        u.z = pk2(v4.x, v5.x); u.w = pk2(v6.x, v7.x);                          \
        *(uint4*)&Abuf[row][(col0) + 0][0] = u;                                \
        u.x = pk2(v0.y, v1.y); u.y = pk2(v2.y, v3.y);                          \
        u.z = pk2(v4.y, v5.y); u.w = pk2(v6.y, v7.y);                          \
        *(uint4*)&Abuf[row][(col0) + 1][0] = u;                                \
        u.x = pk2(v0.z, v1.z); u.y = pk2(v2.z, v3.z);                          \
        u.z = pk2(v4.z, v5.z); u.w = pk2(v6.z, v7.z);                          \
        *(uint4*)&Abuf[row][(col0) + 2][0] = u;                                \
        u.x = pk2(v0.w, v1.w); u.y = pk2(v2.w, v3.w);                          \
        u.z = pk2(v4.w, v5.w); u.w = pk2(v6.w, v7.w);                          \
        *(uint4*)&Abuf[row][(col0) + 3][0] = u;                                \
    }

// ---- pass B (round-3+ proven): bf16-MFMA conv + affine + in-register maxpool + clamp ----
__global__ __launch_bounds__(256, 4) void conv_pool(
    const float* __restrict__ x, const short* __restrict__ Bpack,
    const float* __restrict__ Aarr, const float* __restrict__ B2arr,
    float* __restrict__ out)
{
    __shared__ __align__(16) short Abuf[INROWS_B][ACOLS][8];
    const int prow = blockIdx.x, b = blockIdx.y;
    const int tid = threadIdx.x, wave = tid >> 6, lane = tid & 63;
    const int i = lane & 15, g = lane >> 4;
    const int r0 = prow * 4;

    {
        const float* xb = x + (size_t)b * CIN * HW * HW;
        if (tid < INROWS_B * 33) {
            int row = tid / 33, cg = tid % 33;
            int col0 = cg << 2;
            int ri = r0 + row;
            STAGE_ENTRY(Abuf, xb, row, col0, (row < 6 && cg < 32));
        }
    }

    short8v bq[3][4];
    {
        const uint4* bp = (const uint4*)Bpack;
        #pragma unroll
        for (int dx = 0; dx < 3; ++dx)
            #pragma unroll
            for (int nt = 0; nt < 4; ++nt) {
                uint4 t4 = bp[(dx * 4 + nt) * 64 + lane];
                bq[dx][nt] = *(short8v*)&t4;
            }
    }
    float Ac[4], Bc[4];
    #pragma unroll
    for (int nt = 0; nt < 4; ++nt) {
        Ac[nt] = Aarr[b * COUT + nt * 16 + i];
        Bc[nt] = B2arr[b * COUT + nt * 16 + i];
    }
    __syncthreads();

    for (int tp = 0; tp < 2; ++tp) {
        const int tg = 2 * wave + tp;           // col tile 16*tg
        f32x4 pm[4];
        #pragma unroll
        for (int nt = 0; nt < 4; ++nt) pm[nt] = (f32x4){-1e30f, -1e30f, -1e30f, -1e30f};

        #pragma unroll
        for (int p = 0; p < 2; ++p) {           // conv-row pairs {0,1},{2,3}
            f32x4 acc[2][4];
            #pragma unroll
            for (int rr = 0; rr < 2; ++rr)
                #pragma unroll
                for (int nt = 0; nt < 4; ++nt) acc[rr][nt] = (f32x4){0.f, 0.f, 0.f, 0.f};
            #pragma unroll
            for (int rr = 0; rr < 2; ++rr) {
                const int r = 2 * p + rr;
                #pragma unroll
                for (int dx = 0; dx < 3; ++dx) {
                    short8v a = *(const short8v*)&Abuf[r + g][16 * tg + i + dx][0];
                    #pragma unroll
                    for (int nt = 0; nt < 4; ++nt)
                        acc[rr][nt] = __builtin_amdgcn_mfma_f32_16x16x32_bf16(a, bq[dx][nt], acc[rr][nt], 0, 0, 0);
                }
            }
            #pragma unroll
            for (int nt = 0; nt < 4; ++nt)
                #pragma unroll
                for (int k = 0; k < 4; ++k) {
                    float e0 = fmaf(acc[0][nt][k], Ac[nt], Bc[nt]);
                    float e1 = fmaf(acc[1][nt][k], Ac[nt], Bc[nt]);
                    pm[nt][k] = fmaxf(pm[nt][k], fmaxf(e0, e1));
                }
        }
        const int pc = 4 * tg + g;
        if (pc < PH) {
            #pragma unroll
            for (int nt = 0; nt < 4; ++nt) {
                float m = fmaxf(fmaxf(pm[nt][0], pm[nt][1]), fmaxf(pm[nt][2], pm[nt][3]));
                m = fminf(fmaxf(m, 0.f), 1.f);
                out[((size_t)(b * COUT + nt * 16 + i) * PH + prow) * PH + pc] = m;
            }
        }
    }
}

extern "C" void kernel_launch(void* const* d_in, const int* in_sizes, int n_in,
                              void* d_out, int out_size, void* d_ws, size_t ws_size,
                              hipStream_t stream)
{
    const float* x   = (const float*)d_in[0];
    const float* w   = (const float*)d_in[1];
    const float* cbv = (const float*)d_in[2];
    const float* gnw = (const float*)d_in[3];
    const float* gnb = (const float*)d_in[4];
    const float* sc  = (const float*)d_in[5];
    float* out = (float*)d_out;

    float* part  = (float*)d_ws;                 // 128*16*16*2 = 65536 f32
    float* Aarr  = part + 65536;                 // 8192 f32
    float* B2arr = Aarr + 8192;                  // 8192 f32
    short* Bpack = (short*)(B2arr + 8192);       // 6144 bf16

    prep_weights<<<dim3(1), 256, 0, stream>>>(w, Bpack);
    conv_stats<<<dim3(STRIPS_A, BATCH), 256, 0, stream>>>(x, Bpack, cbv, part);
    finalize_stats<<<dim3(8), 256, 0, stream>>>(part, gnw, gnb, sc, cbv, Aarr, B2arr);
    conv_pool<<<dim3(PH, BATCH), 256, 0, stream>>>(x, Bpack, Aarr, B2arr, out);
}

// Round 7
// 68.920 us; speedup vs baseline: 2.9948x; 1.2319x over previous
//
#include <hip/hip_runtime.h>

typedef __attribute__((ext_vector_type(8))) short short8v;
typedef __attribute__((ext_vector_type(4))) float f32x4;
typedef __attribute__((ext_vector_type(4))) int i32x4;

#define BATCH 128
#define CIN 8
#define HW 128
#define COUT 64
#define OHW 126
#define NG 16
#define PH 31
#define GN_EPS 1e-5f

#define ROWS_A 8
#define STRIPS_A 16
#define INROWS_A 11   // 10 real + 1 zero pad (for g=3 reads)
#define ACOLS 132

static __device__ __forceinline__ unsigned short f2bf(float f) {
    unsigned u = __float_as_uint(f);
    return (unsigned short)((u + 0x7fffu + ((u >> 16) & 1u)) >> 16);
}
static __device__ __forceinline__ unsigned pk2(float a, float b) {
    return (unsigned)f2bf(a) | ((unsigned)f2bf(b) << 16);
}

// ---- prep: pack weights into MFMA B-fragment order, bf16 ----
__global__ __launch_bounds__(256) void prep_weights(const float* __restrict__ w,
                                                    short* __restrict__ Bpack)
{
    for (int e = threadIdx.x; e < 3 * 4 * 64; e += 256) {
        int dx = e >> 8;
        int nt = (e >> 6) & 3;
        int l  = e & 63;
        int i = l & 15, g = l >> 4;
        int n = nt * 16 + i;
        #pragma unroll
        for (int j = 0; j < 8; ++j) {
            float v = (g < 3) ? w[((n * CIN + j) * 3 + g) * 3 + dx] : 0.f;
            Bpack[e * 8 + j] = (short)f2bf(v);
        }
    }
}

// ---- pass A: bf16-MFMA conv ONCE: per-(b,group) partial stats + sign-folded
//      pooled window maxes (mz) written to ws. Wave split: myprow = wave&1
//      (owns whole 4-row pool windows), t-half = wave>>1. ----
__global__ __launch_bounds__(256, 4) void conv_fused(
    const float* __restrict__ x, const short* __restrict__ Bpack,
    const float* __restrict__ bias, const float* __restrict__ gnw,
    const float* __restrict__ scale, float* __restrict__ part,
    float* __restrict__ mzbuf)
{
    __shared__ __align__(16) short Abuf[INROWS_A][ACOLS][8];
    __shared__ float red[4][NG][2];
    const int strip = blockIdx.x, b = blockIdx.y;
    const int tid = threadIdx.x, wave = tid >> 6, lane = tid & 63;
    const int i = lane & 15, g = lane >> 4;
    const int r0 = strip * ROWS_A;

    // B fragments into registers (12 x 16B) — round-2 verbatim
    short8v bq[3][4];
    {
        const i32x4* bp = (const i32x4*)Bpack;
        #pragma unroll
        for (int dx = 0; dx < 3; ++dx)
            #pragma unroll
            for (int nt = 0; nt < 4; ++nt) {
                i32x4 v = bp[(dx * 4 + nt) * 64 + lane];
                bq[dx][nt] = *(short8v*)&v;
            }
    }
    float bs[4], sgn[4];
    #pragma unroll
    for (int nt = 0; nt < 4; ++nt) {
        int c = nt * 16 + i;
        bs[nt] = bias[c];
        sgn[nt] = copysignf(1.f, gnw[c] * scale[c]);
    }

    // staging — round-2 verbatim
    {
        const float* xb = x + (size_t)b * CIN * HW * HW;
        for (int e = tid; e < INROWS_A * ACOLS; e += 256) {
            int row = e / ACOLS, col = e % ACOLS;
            int ri = r0 + row;
            bool ok = (row < 10) && (ri < HW) && (col < HW);
            unsigned pk0, pk1, pk2_, pk3;
            {
                const float* base = &xb[(size_t)ri * HW + col];
                float v0 = ok ? base[0 * HW * HW] : 0.f;
                float v1 = ok ? base[1 * HW * HW] : 0.f;
                float v2 = ok ? base[2 * HW * HW] : 0.f;
                float v3 = ok ? base[3 * HW * HW] : 0.f;
                float v4 = ok ? base[4 * HW * HW] : 0.f;
                float v5 = ok ? base[5 * HW * HW] : 0.f;
                float v6 = ok ? base[6 * HW * HW] : 0.f;
                float v7 = ok ? base[7 * HW * HW] : 0.f;
                pk0  = pk2(v0, v1);
                pk1  = pk2(v2, v3);
                pk2_ = pk2(v4, v5);
                pk3  = pk2(v6, v7);
            }
            uint4 w4 = make_uint4(pk0, pk1, pk2_, pk3);
            *(uint4*)&Abuf[row][col][0] = w4;
        }
    }
    __syncthreads();

    float s1[4] = {0.f, 0.f, 0.f, 0.f}, s2[4] = {0.f, 0.f, 0.f, 0.f};
    const int myprow = wave & 1;        // pool row within strip
    const int tbase  = (wave >> 1) * 4; // t-half
    const int prow_g = strip * 2 + myprow;

    for (int tl = 0; tl < 4; ++tl) {
        const int t = tbase + tl;
        float mz[4] = {-3e38f, -3e38f, -3e38f, -3e38f};
        #pragma unroll
        for (int ri_ = 0; ri_ < 4; ++ri_) {
            const int rloc = 4 * myprow + ri_;
            if (r0 + rloc < OHW) {
                f32x4 acc[4];
                #pragma unroll
                for (int nt = 0; nt < 4; ++nt) acc[nt] = (f32x4){0.f, 0.f, 0.f, 0.f};
                #pragma unroll
                for (int dx = 0; dx < 3; ++dx) {
                    short8v a = *(const short8v*)&Abuf[rloc + g][16 * t + i + dx][0];
                    #pragma unroll
                    for (int nt = 0; nt < 4; ++nt)
                        acc[nt] = __builtin_amdgcn_mfma_f32_16x16x32_bf16(a, bq[dx][nt], acc[nt], 0, 0, 0);
                }
                const int nv = (t == 7 && g == 3) ? 2 : 4;  // cols >=126 invalid
                #pragma unroll
                for (int nt = 0; nt < 4; ++nt)
                    #pragma unroll
                    for (int r = 0; r < 4; ++r)
                        if (r < nv) {
                            float v = acc[nt][r] + bs[nt];
                            s1[nt] += v;
                            s2[nt] = fmaf(v, v, s2[nt]);
                            mz[nt] = fmaxf(mz[nt], v * sgn[nt]);
                        }
            }
        }
        const int pc = 4 * t + g;
        if (prow_g < PH && pc < PH) {
            float* dst = &mzbuf[((size_t)(b * PH + prow_g) * 32 + pc) * 64 + i];
            #pragma unroll
            for (int nt = 0; nt < 4; ++nt) dst[nt * 16] = mz[nt];
        }
    }

    // stats reduce — round-2 verbatim
    #pragma unroll
    for (int nt = 0; nt < 4; ++nt) {
        s1[nt] += __shfl_xor(s1[nt], 1);  s1[nt] += __shfl_xor(s1[nt], 2);
        s1[nt] += __shfl_xor(s1[nt], 16); s1[nt] += __shfl_xor(s1[nt], 32);
        s2[nt] += __shfl_xor(s2[nt], 1);  s2[nt] += __shfl_xor(s2[nt], 2);
        s2[nt] += __shfl_xor(s2[nt], 16); s2[nt] += __shfl_xor(s2[nt], 32);
    }
    if (g == 0 && (i & 3) == 0) {
        #pragma unroll
        for (int nt = 0; nt < 4; ++nt) {
            red[wave][nt * 4 + (i >> 2)][0] = s1[nt];
            red[wave][nt * 4 + (i >> 2)][1] = s2[nt];
        }
    }
    __syncthreads();
    if (tid < 32) {
        int grp = tid >> 1, which = tid & 1;
        float v = red[0][grp][which] + red[1][grp][which] + red[2][grp][which] + red[3][grp][which];
        part[(((size_t)b * STRIPS_A + strip) * NG + grp) * 2 + which] = v;
    }
}

// ---- fold stats into per-(b,c): A2 = A*sgn (>=0), Bv ----
__global__ __launch_bounds__(256) void finalize_stats(
    const float* __restrict__ part, const float* __restrict__ gnw,
    const float* __restrict__ gnb, const float* __restrict__ scale,
    float* __restrict__ A2arr, float* __restrict__ Bvarr)
{
    int t = blockIdx.x * 256 + threadIdx.x;
    if (t >= BATCH * NG) return;
    int b = t >> 4, grp = t & 15;
    float s1 = 0.f, s2 = 0.f;
    for (int s = 0; s < STRIPS_A; ++s) {
        s1 += part[(((size_t)b * STRIPS_A + s) * NG + grp) * 2 + 0];
        s2 += part[(((size_t)b * STRIPS_A + s) * NG + grp) * 2 + 1];
    }
    const float invN = 1.f / (float)(4 * OHW * OHW);
    float mean = s1 * invN;
    float var = s2 * invN - mean * mean;
    float rstd = rsqrtf(var + GN_EPS);
    #pragma unroll
    for (int ci = 0; ci < 4; ++ci) {
        int c = grp * 4 + ci;
        float gs = gnw[c] * scale[c];
        float A = rstd * gs;
        float sg = copysignf(1.f, gs);
        float Bv = (gnb[c] - mean * rstd * gnw[c]) * scale[c];
        A2arr[b * COUT + c] = A * sg;   // = rstd*|gs| >= 0
        Bvarr[b * COUT + c] = Bv;
    }
}

// ---- pass B: affine + clamp + transpose-write (memory-bound) ----
__global__ __launch_bounds__(256) void affine_pool(
    const float* __restrict__ mzbuf, const float* __restrict__ A2arr,
    const float* __restrict__ Bvarr, float* __restrict__ out)
{
    __shared__ float sl[PH * 65];   // [pw][c], stride 65 (bank-spread)
    const int ph = blockIdx.x, b = blockIdx.y;
    const int tid = threadIdx.x;

    const float* src = mzbuf + (size_t)(b * PH + ph) * 32 * 64;
    for (int e = tid; e < PH * 64; e += 256) {
        int pc = e >> 6, c = e & 63;
        sl[pc * 65 + c] = src[pc * 64 + c];
    }
    __syncthreads();

    const int c = tid >> 2, q = tid & 3;
    const float A2 = A2arr[b * COUT + c];
    const float B0 = Bvarr[b * COUT + c];
    float* ob = out + (size_t)(b * COUT + c) * (PH * PH) + ph * PH;
    #pragma unroll
    for (int k = 0; k < 8; ++k) {
        int pw = q * 8 + k;
        if (pw < PH) {
            float v = fmaf(A2, sl[pw * 65 + c], B0);
            ob[pw] = fminf(fmaxf(v, 0.f), 1.f);
        }
    }
}

extern "C" void kernel_launch(void* const* d_in, const int* in_sizes, int n_in,
                              void* d_out, int out_size, void* d_ws, size_t ws_size,
                              hipStream_t stream)
{
    const float* x   = (const float*)d_in[0];
    const float* w   = (const float*)d_in[1];
    const float* cbv = (const float*)d_in[2];
    const float* gnw = (const float*)d_in[3];
    const float* gnb = (const float*)d_in[4];
    const float* sc  = (const float*)d_in[5];
    float* out = (float*)d_out;

    float* mzbuf = (float*)d_ws;                       // 128*31*32*64 f32 = 32.5 MB
    float* part  = mzbuf + (size_t)BATCH * PH * 32 * 64;  // 65536 f32
    float* A2arr = part + 65536;                       // 8192 f32
    float* Bvarr = A2arr + 8192;                       // 8192 f32
    short* Bpack = (short*)(Bvarr + 8192);             // 6144 bf16

    prep_weights<<<dim3(1), 256, 0, stream>>>(w, Bpack);
    conv_fused<<<dim3(STRIPS_A, BATCH), 256, 0, stream>>>(x, Bpack, cbv, gnw, sc, part, mzbuf);
    finalize_stats<<<dim3(8), 256, 0, stream>>>(part, gnw, gnb, sc, A2arr, Bvarr);
    affine_pool<<<dim3(PH, BATCH), 256, 0, stream>>>(mzbuf, A2arr, Bvarr, out);
}